// Round 3
// baseline (1198.513 us; speedup 1.0000x reference)
//
#include <hip/hip_runtime.h>
#include <math.h>

#define Bc   2
#define Hc   240
#define Wc   1216
#define CHG  64
#define HWc  (Hc*Wc)          // 291840
#define NPIX (Bc*HWc)         // 583680

// d_out layout (floats): [feat NPIX][offset 2*18*HW][aff 9*HW*2b]
#define OUT1 (NPIX)
#define OUT2 (OUT1 + Bc*18*HWc)

// ws layout (floats): wr[13824] | buf0[NPIX] | buf1[NPIX] | off_pk[8*NPIX u32] | aff_pk[8*NPIX u16]
#define WS_WR    0
#define WS_BUF0  (13824)
#define WS_BUF1  (WS_BUF0 + NPIX)
#define WS_OFFPK (WS_BUF1 + NPIX)            // as u32 index
#define WS_AFFPK (WS_OFFPK + 8*NPIX)         // u32 units; aff_pk is u16* at this u32 offset

__device__ __forceinline__ unsigned short f2bf(float x) {
    unsigned u = __float_as_uint(x);
    unsigned r = (u + 0x7fffu + ((u >> 16) & 1u)) >> 16;
    return (unsigned short)r;
}
__device__ __forceinline__ float bf2f(unsigned short u) {
    return __uint_as_float(((unsigned)u) << 16);
}

// zero-padded bilinear sample from a (Hc,Wc) plane
__device__ __forceinline__ float bilin(const float* __restrict__ f, float ys, float xs) {
    float y0f = floorf(ys), x0f = floorf(xs);
    float wy1 = ys - y0f,   wx1 = xs - x0f;
    float wy0 = 1.f - wy1,  wx0 = 1.f - wx1;
    int y0 = (int)y0f, x0 = (int)x0f;
    int y1 = y0 + 1,   x1 = x0 + 1;
    int y0c = min(max(y0, 0), Hc-1), y1c = min(max(y1, 0), Hc-1);
    int x0c = min(max(x0, 0), Wc-1), x1c = min(max(x1, 0), Wc-1);
    float my0 = (y0 >= 0 && y0 < Hc) ? 1.f : 0.f;
    float my1 = (y1 >= 0 && y1 < Hc) ? 1.f : 0.f;
    float mx0 = (x0 >= 0 && x0 < Wc) ? 1.f : 0.f;
    float mx1 = (x1 >= 0 && x1 < Wc) ? 1.f : 0.f;
    float v00 = f[y0c*Wc + x0c] * (my0*mx0);
    float v01 = f[y0c*Wc + x1c] * (my0*mx1);
    float v10 = f[y1c*Wc + x0c] * (my1*mx0);
    float v11 = f[y1c*Wc + x1c] * (my1*mx1);
    return wy0*(wx0*v00 + wx1*v01) + wy1*(wx0*v10 + wx1*v11);
}

// reorder w_oa (24,64,3,3) -> wr[(c*9+j)*24 + oc]
__global__ void reorder_w(const float* __restrict__ w_oa, float* __restrict__ wr) {
    int i = blockIdx.x*256 + threadIdx.x;   // over 24*576
    if (i < 24*576) {
        int oc = i / 576; int cj = i - oc*576;
        wr[cj*24 + oc] = w_oa[i];
    }
}

// fused: 3x3 conv (64->24), 4 px/thread + epilogue + packed bf16 tap data + feat init
__global__ __launch_bounds__(256) void conv_epilogue(
    const float* __restrict__ guid, const float* __restrict__ conf,
    const float* __restrict__ wr,   const float* __restrict__ b_oa,
    const float* __restrict__ aff_scale,
    const float* __restrict__ feat_init, const float* __restrict__ feat_fix,
    float* __restrict__ dout, float* __restrict__ buf0,
    unsigned* __restrict__ off_pk, unsigned short* __restrict__ aff_pk)
{
    // bijective chunked XCD swizzle (8 XCDs): round-robin bid -> contiguous chunks
    int nwg = gridDim.x;                 // 570
    int q = nwg >> 3, r = nwg & 7;
    int xcd = blockIdx.x & 7, pos = blockIdx.x >> 3;
    int sb = (xcd < r ? xcd*(q+1) : r*(q+1) + (xcd - r)*q) + pos;

    int gp = sb*256 + threadIdx.x;       // pixel-group id over NPIX/4
    int b   = gp / (HWc/4);
    int rem = gp - b*(HWc/4);
    int h   = rem / (Wc/4);
    int wq  = rem - h*(Wc/4);
    int w0  = wq * 4;

    // row offsets / validity for the 3 dy taps
    int   rowoff[3]; bool okY[3];
    #pragma unroll
    for (int dy = 0; dy < 3; ++dy) {
        int hy = h + dy - 1;
        okY[dy]   = (hy >= 0) & (hy < Hc);
        rowoff[3-1-(2-dy)] = min(max(hy, 0), Hc-1) * Wc;   // = rowoff[dy]
    }
    bool lok = (wq > 0);
    bool rok = (wq < (Wc/4 - 1));

    float acc[24][4];
    #pragma unroll
    for (int oc = 0; oc < 24; ++oc) {
        float bv = b_oa[oc];
        #pragma unroll
        for (int px = 0; px < 4; ++px) acc[oc][px] = bv;
    }

    const float* gb = guid + (size_t)b*CHG*HWc;
    for (int c = 0; c < CHG; ++c) {
        const float* gc = gb + c*HWc;
        const float* wcp = wr + c*216;
        #pragma unroll
        for (int dy = 0; dy < 3; ++dy) {
            const float* rp = gc + rowoff[dy];
            float V[6];
            if (okY[dy]) {
                float4 vm = *(const float4*)(rp + w0);
                V[0] = lok ? rp[w0-1] : 0.f;
                V[1] = vm.x; V[2] = vm.y; V[3] = vm.z; V[4] = vm.w;
                V[5] = rok ? rp[w0+4] : 0.f;
            } else {
                #pragma unroll
                for (int i = 0; i < 6; ++i) V[i] = 0.f;
            }
            #pragma unroll
            for (int dx = 0; dx < 3; ++dx) {
                const float* wj = wcp + (dy*3+dx)*24;
                #pragma unroll
                for (int oc = 0; oc < 24; ++oc) {
                    float wv = wj[oc];
                    acc[oc][0] = fmaf(V[dx+0], wv, acc[oc][0]);
                    acc[oc][1] = fmaf(V[dx+1], wv, acc[oc][1]);
                    acc[oc][2] = fmaf(V[dx+2], wv, acc[oc][2]);
                    acc[oc][3] = fmaf(V[dx+3], wv, acc[oc][3]);
                }
            }
        }
    }

    // epilogue: tap k -> (offy, offx) = (acc[2k], acc[2k+1]), aff raw = acc[16+k]
    float scale = 1.f / (aff_scale[0] + 1e-8f);
    const float* cb = conf + (size_t)b*HWc;
    float af[8][4], aref[4];
    #pragma unroll
    for (int px = 0; px < 4; ++px) {
        float av[8]; float ssum = 0.f;
        #pragma unroll
        for (int k = 0; k < 8; ++k) {
            float a  = tanhf(acc[16+k][px]) * scale;
            float ys = (float)h        + acc[2*k  ][px];
            float xs = (float)(w0+px)  + acc[2*k+1][px];
            a *= bilin(cb, ys, xs);
            av[k] = a; ssum += fabsf(a);
        }
        float inv = 1.f / fmaxf(ssum + 1e-4f, 1.f);
        float s2 = 0.f;
        #pragma unroll
        for (int k = 0; k < 8; ++k) { av[k] *= inv; s2 += av[k]; af[k][px] = av[k]; }
        aref[px] = 1.f - s2;
    }

    int hw0 = h*Wc + w0;
    float* ob = dout + OUT1 + (size_t)b*18*HWc + hw0;
    float* ab = dout + OUT2 + (size_t)b*9*HWc  + hw0;
    #pragma unroll
    for (int kf = 0; kf < 9; ++kf) {
        float4 vy, vx, va;
        if (kf == 4) {
            vy = make_float4(0.f,0.f,0.f,0.f);
            vx = make_float4(0.f,0.f,0.f,0.f);
            va = make_float4(aref[0], aref[1], aref[2], aref[3]);
        } else {
            int k = (kf < 4) ? kf : kf-1;
            vy = make_float4(acc[2*k  ][0], acc[2*k  ][1], acc[2*k  ][2], acc[2*k  ][3]);
            vx = make_float4(acc[2*k+1][0], acc[2*k+1][1], acc[2*k+1][2], acc[2*k+1][3]);
            va = make_float4(af[k][0], af[k][1], af[k][2], af[k][3]);
        }
        *(float4*)(ob + (size_t)(2*kf  )*HWc) = vy;
        *(float4*)(ob + (size_t)(2*kf+1)*HWc) = vx;
        *(float4*)(ab + (size_t)kf*HWc)       = va;
    }

    // packed bf16 tap data for propagation (8 non-center taps)
    unsigned*       opk = off_pk + (size_t)(b*8)*HWc + hw0;
    unsigned short* apk = aff_pk + (size_t)(b*8)*HWc + hw0;
    #pragma unroll
    for (int k = 0; k < 8; ++k) {
        uint4 pk;
        pk.x = (unsigned)f2bf(acc[2*k][0]) | ((unsigned)f2bf(acc[2*k+1][0]) << 16);
        pk.y = (unsigned)f2bf(acc[2*k][1]) | ((unsigned)f2bf(acc[2*k+1][1]) << 16);
        pk.z = (unsigned)f2bf(acc[2*k][2]) | ((unsigned)f2bf(acc[2*k+1][2]) << 16);
        pk.w = (unsigned)f2bf(acc[2*k][3]) | ((unsigned)f2bf(acc[2*k+1][3]) << 16);
        *(uint4*)(opk + (size_t)k*HWc) = pk;
        ushort4 aa;
        aa.x = f2bf(af[k][0]); aa.y = f2bf(af[k][1]);
        aa.z = f2bf(af[k][2]); aa.w = f2bf(af[k][3]);
        *(ushort4*)(apk + (size_t)k*HWc) = aa;
    }

    // init masked feature buffer
    int p0 = b*HWc + hw0;
    float4 ff4 = *(const float4*)(feat_fix  + p0);
    float4 fi4 = *(const float4*)(feat_init + p0);
    float4 o;
    o.x = (ff4.x > 0.f) ? ff4.x : fi4.x;
    o.y = (ff4.y > 0.f) ? ff4.y : fi4.y;
    o.z = (ff4.z > 0.f) ? ff4.z : fi4.z;
    o.w = (ff4.w > 0.f) ? ff4.w : fi4.w;
    *(float4*)(buf0 + p0) = o;
}

// one propagation step: 8 bf16-packed deformable taps + exact center tap
__global__ __launch_bounds__(256) void prop_step(
    const float* __restrict__ fin,
    const unsigned* __restrict__ off_pk,
    const unsigned short* __restrict__ aff_pk,
    const float* __restrict__ feat_fix,
    float* __restrict__ out, int apply_mask)
{
    int p  = blockIdx.x*256 + threadIdx.x;
    int b  = p / HWc;
    int hw = p - b*HWc;
    int h  = hw / Wc;
    int w  = hw - h*Wc;

    const float* fb = fin + (size_t)b*HWc;
    const unsigned*       opk = off_pk + (size_t)(b*8)*HWc + hw;
    const unsigned short* apk = aff_pk + (size_t)(b*8)*HWc + hw;

    float s = 0.f, asum = 0.f;
    #pragma unroll
    for (int k = 0; k < 8; ++k) {
        int kf = (k < 4) ? k : k+1;
        unsigned pk = opk[(size_t)k*HWc];
        float offy = bf2f((unsigned short)(pk & 0xffffu));
        float offx = bf2f((unsigned short)(pk >> 16));
        float a    = bf2f(apk[(size_t)k*HWc]);
        float ys = (float)(h + kf/3 - 1) + offy;
        float xs = (float)(w + kf%3 - 1) + offx;
        s += a * bilin(fb, ys, xs);
        asum += a;
    }
    s += (1.f - asum) * fb[hw];   // center tap: zero offset, aref = 1 - sum(aff)

    if (apply_mask) {
        float ff = feat_fix[p];
        out[p] = (ff > 0.f) ? ff : s;
    } else {
        out[p] = s;
    }
}

extern "C" void kernel_launch(void* const* d_in, const int* in_sizes, int n_in,
                              void* d_out, int out_size, void* d_ws, size_t ws_size,
                              hipStream_t stream) {
    const float* feat_init  = (const float*)d_in[0];
    const float* guidance   = (const float*)d_in[1];
    const float* confidence = (const float*)d_in[2];
    const float* feat_fix   = (const float*)d_in[3];
    const float* w_oa       = (const float*)d_in[4];
    const float* b_oa       = (const float*)d_in[5];
    const float* aff_scale  = (const float*)d_in[6];
    float* out = (float*)d_out;

    float* wsf = (float*)d_ws;
    float* wr   = wsf + WS_WR;
    float* buf0 = wsf + WS_BUF0;
    float* buf1 = wsf + WS_BUF1;
    unsigned*       off_pk = (unsigned*)(wsf + WS_OFFPK);
    unsigned short* aff_pk = (unsigned short*)(wsf + WS_AFFPK);

    reorder_w<<<(24*576 + 255)/256, 256, 0, stream>>>(w_oa, wr);
    conv_epilogue<<<(NPIX/4)/256, 256, 0, stream>>>(
        guidance, confidence, wr, b_oa, aff_scale, feat_init, feat_fix,
        out, buf0, off_pk, aff_pk);

    float* bufs[2] = {buf0, buf1};
    for (int i = 1; i <= 18; ++i) {
        const float* fi = bufs[(i-1) & 1];
        float* fo = (i == 18) ? out : bufs[i & 1];
        prop_step<<<NPIX/256, 256, 0, stream>>>(fi, off_pk, aff_pk, feat_fix, fo, (i < 18) ? 1 : 0);
    }
}